// Round 7
// baseline (311.076 us; speedup 1.0000x reference)
//
#include <hip/hip_runtime.h>
#include <stdint.h>
#include <math.h>

// Problem constants
constexpr int Kk  = 1024;

// d_out layout (floats)
constexpr int OUT0_N   = 32 * 64 * 1024;       // 2097152 (z_st, [B,D,H,W])
constexpr int OUT_LOSS = OUT0_N;               // 2097152
constexpr int OUT_PERP = OUT0_N + 1;           // 2097153
constexpr int OUT_ENC  = OUT0_N + 2;           // 2097154

// d_ws layout (bytes) — everything fully written each call (ws is poisoned):
//   [0      .. 4096)     counts u32[1024]     (zeroed by norms block 0)
//   [4096   .. 12288)    loss partials double[1024] (fully written by finish)
//   [12288  .. 16384)    Bn_g f32[1024]       exact code norms (norms_kernel)
//   [16384  .. 16400)    maxbn f32[4]         per-block max norm partials
//   [16400  .. 1064976)  lockey u32[32768][8] per-(row,cg) cnt+3x10b candidate
//                        codes — PLAIN stores, fully written by dist.
// R11: lockey u64->u32 (no f32 lmin; finish rechecks ALL cgs' candidates in
// parallel, union <= 24/row — prune unnecessary). Bn precomputed once.
constexpr size_t WS_CNT = 0;
constexpr size_t WS_LP  = 4096;
constexpr size_t WS_BN  = 12288;
constexpr size_t WS_MBN = 16384;
constexpr size_t WS_KEY = 16400;

typedef short bf16x8 __attribute__((ext_vector_type(8)));
typedef float f32x16 __attribute__((ext_vector_type(16)));

// ---------------------------------------------------------------------------
// numpy-bit-exact 64-elem squared-norm: tt[d]=fl(x*x), 8 stride-8 sequential
// accumulators, pairwise combine. Contraction OFF. p: 16B-aligned, contiguous.
// ---------------------------------------------------------------------------
__device__ __forceinline__ float norm64v(const float4* __restrict__ p) {
#pragma clang fp contract(off)
    float tt[64];
#pragma unroll
    for (int q = 0; q < 16; ++q) {
        float4 v = p[q];
        tt[4 * q + 0] = v.x * v.x;
        tt[4 * q + 1] = v.y * v.y;
        tt[4 * q + 2] = v.z * v.z;
        tt[4 * q + 3] = v.w * v.w;
    }
    float r[8];
#pragma unroll
    for (int j = 0; j < 8; ++j) r[j] = tt[j];
#pragma unroll
    for (int i = 8; i < 64; i += 8)
#pragma unroll
        for (int j = 0; j < 8; ++j) r[j] += tt[i + j];
    return ((r[0] + r[1]) + (r[2] + r[3])) + ((r[4] + r[5]) + (r[6] + r[7]));
}

__device__ __forceinline__ uint32_t fsort(float f) {
    uint32_t b = __float_as_uint(f);
    return (b & 0x80000000u) ? ~b : (b | 0x80000000u);
}

// RNE float->bf16 (finite inputs only; data is well inside normal range)
__device__ __forceinline__ unsigned short f2bf(float f) {
    uint32_t u = __float_as_uint(f);
    uint32_t r = (u + 0x7fffu + ((u >> 16) & 1u)) >> 16;
    return (unsigned short)r;
}

// exact distance key, bit-identical to the R5/R7 exact kernel; Bn_g holds the
// bit-exact norm64v value (computed once in norms_kernel from the same data).
__device__ __forceinline__ unsigned long long
exact_key_bn(float A, const float* __restrict__ xr, const float* __restrict__ emb,
             const float* __restrict__ Bn_g, uint32_t code) {
    const float* er = emb + (size_t)code * 64;
    float C = 0.f;
#pragma unroll
    for (int d = 0; d < 64; ++d) C = __builtin_fmaf(xr[d], er[d], C);
    float s = A + Bn_g[code];
    float dist = __builtin_fmaf(-2.f, C, s);
    return ((unsigned long long)fsort(dist) << 32) | code;
}

// ---------------------------------------------------------------------------
// norms_kernel: 4 blocks x 256 thr — exact code norms ONCE (they were being
// recomputed in all 2048 dist blocks), per-block max partials, counts zero.
// ---------------------------------------------------------------------------
__global__ __launch_bounds__(256)
void norms_kernel(const float* __restrict__ emb, float* __restrict__ Bn_g,
                  float* __restrict__ maxbn, uint32_t* __restrict__ counts) {
    __shared__ float wred[4];
    const int t = threadIdx.x, lane = t & 63, wv = t >> 6;
    const int code = blockIdx.x * 256 + t;
    float nn = norm64v((const float4*)(emb + (size_t)code * 64));
    Bn_g[code] = nn;
    if (blockIdx.x == 0) ((uint4*)counts)[t] = make_uint4(0u, 0u, 0u, 0u);
    float mx = nn;
#pragma unroll
    for (int m = 1; m < 64; m <<= 1) mx = fmaxf(mx, __shfl_xor(mx, m, 64));
    if (lane == 0) wred[wv] = mx;
    __syncthreads();
    if (t == 0) maxbn[blockIdx.x] = fmaxf(fmaxf(wred[0], wred[1]), fmaxf(wred[2], wred[3]));
}

// ---------------------------------------------------------------------------
// dist_mfma (R11): 2048 blocks = 256 rowgroups x 8 codegroups, 256 thr,
// ~17 KB LDS, 4 blk/CU. Screen: s_hat = Bn_exact - 2*(x.e)_bf16 via
// mfma_32x32x16_bf16; margin 0.017*sqrt(xsq*maxBn)+1e-4 (validated R6/R8/R9,
// absmax 0.0 each time). Changes vs R9 (structure/plumbing only, math same):
//  - x B-fragments built DIRECTLY from global into registers (same
//    (s,g,e)->d map as R6's validated build) — x-LDS + swizzle + one
//    barrier removed
//  - Bn_s loaded from precomputed Bn_g (bit-identical values)
//  - lockey u32 (candidates only; no lmin — finish rechecks all candidates)
// Enc zero-fill interleave kept verbatim (R10 A/B: it is ~free here).
// ---------------------------------------------------------------------------
__global__ __launch_bounds__(256, 4)
void dist_mfma(const float* __restrict__ z_e, const float* __restrict__ emb,
               const float* __restrict__ Bn_g, const float* __restrict__ maxbn,
               uint32_t* __restrict__ lockey, float* __restrict__ out) {
    __shared__ unsigned short ebf[128 * 64];   // 16 KB bf16 codes, swizzled
    __shared__ float Bn_s[128];
    const int t = threadIdx.x, lane = t & 63, wv = t >> 6, g = lane >> 5;
    const int rg = blockIdx.x >> 3, cg = blockIdx.x & 7;
    const int n0 = rg * 128, b = n0 >> 10, hw0 = n0 & 1023;
    const float* zb = z_e + (size_t)b * 65536 + hw0;

    // ---- e-tile: contiguous 32 KB fp32 -> bf16 LDS (swizzled) ----
    {
        const float4* ep = (const float4*)(emb + (size_t)cg * 8192);
#pragma unroll
        for (int it = 0; it < 8; ++it) {
            int j = t + it * 256;            // 0..2047
            float4 v = ep[j];
            int code = j >> 4, q = j & 15;
            ushort4 bv;
            bv.x = f2bf(v.x); bv.y = f2bf(v.y); bv.z = f2bf(v.z); bv.w = f2bf(v.w);
            *(ushort4*)((char*)ebf + code * 128 + ((q * 8) ^ ((code & 7) << 4))) = bv;
        }
    }
    if (t < 128) Bn_s[t] = Bn_g[cg * 128 + t];    // bit-exact precomputed norms

    // ---- x B-fragments: straight from global to registers (no LDS) ----
    const int rowl = wv * 32 + (lane & 31);
    float xsq = 0.f;
    bf16x8 bfr[4];
#pragma unroll
    for (int s = 0; s < 4; ++s) {
        bf16x8 f;
#pragma unroll
        for (int e = 0; e < 8; ++e) {
            int d = s * 16 + g * 8 + e;
            float x = zb[(size_t)d * 1024 + rowl];
            xsq = __builtin_fmaf(x, x, xsq);
            f[e] = (short)f2bf(x);
        }
        bfr[s] = f;
    }
    xsq += __shfl_xor(xsq, 32, 64);          // partner half holds other 32 d's
    const float mbn = fmaxf(fmaxf(maxbn[0], maxbn[1]), fmaxf(maxbn[2], maxbn[3]));
    const float margin = 0.017f * sqrtf(xsq * mbn) + 1.0e-4f;
    __syncthreads();

    const int swz = (lane & 7) << 4;
    const char* ebase = (const char*)ebf + (lane & 31) * 128;

    float4* encz = (float4*)(out + OUT_ENC) + (size_t)blockIdx.x * 4096;
    const float4 zero4 = make_float4(0.f, 0.f, 0.f, 0.f);

    // ---- pass 1: row min of s_hat (enc-fill stores ride along) ----
    float runmin = 3.4e38f;
#pragma unroll 1
    for (int tm = 0; tm < 4; ++tm) {
        encz[(size_t)(tm * 2 + 0) * 256 + t] = zero4;
        encz[(size_t)(tm * 2 + 1) * 256 + t] = zero4;
        const char* p = ebase + tm * 4096;
        f32x16 acc = {};
#pragma unroll
        for (int s = 0; s < 4; ++s)
            acc = __builtin_amdgcn_mfma_f32_32x32x16_bf16(
                *(const bf16x8*)(p + ((s * 32 + g * 16) ^ swz)), bfr[s], acc, 0, 0, 0);
#pragma unroll
        for (int r = 0; r < 16; ++r) {
            int cl = tm * 32 + (r & 3) + 8 * (r >> 2) + 4 * g;
            runmin = fminf(runmin, __builtin_fmaf(-2.f, acc[r], Bn_s[cl]));
        }
    }
    runmin = fminf(runmin, __shfl_xor(runmin, 32, 64));   // lane pair = same row
    const float thr = runmin + margin;

    // ---- pass 2: collect candidates (<=3/lane; MFMA recompute, cheap) ----
    uint32_t cnt = 0, c0 = 0, c1 = 0, c2 = 0;
#pragma unroll 1
    for (int tm = 0; tm < 4; ++tm) {
        encz[(size_t)(8 + tm * 2 + 0) * 256 + t] = zero4;
        encz[(size_t)(8 + tm * 2 + 1) * 256 + t] = zero4;
        const char* p = ebase + tm * 4096;
        f32x16 acc = {};
#pragma unroll
        for (int s = 0; s < 4; ++s)
            acc = __builtin_amdgcn_mfma_f32_32x32x16_bf16(
                *(const bf16x8*)(p + ((s * 32 + g * 16) ^ swz)), bfr[s], acc, 0, 0, 0);
#pragma unroll
        for (int r = 0; r < 16; ++r) {
            int cl = tm * 32 + (r & 3) + 8 * (r >> 2) + 4 * g;
            float sv = __builtin_fmaf(-2.f, acc[r], Bn_s[cl]);
            if (sv <= thr) {
                uint32_t gc = (uint32_t)(cg * 128 + cl);
                if (cnt == 0u) c0 = gc; else if (cnt == 1u) c1 = gc; else if (cnt == 2u) c2 = gc;
                ++cnt;
            }
        }
    }
    // merge with partner lane (lane^32: other code-subset of the same row)
    uint32_t pc = __shfl_xor(cnt, 32, 64);
    uint32_t p0 = __shfl_xor(c0, 32, 64);
    uint32_t p1 = __shfl_xor(c1, 32, 64);
    uint32_t p2 = __shfl_xor(c2, 32, 64);
    if (lane < 32) {
        uint32_t tot = cnt + pc;
        uint32_t lo;
        if (tot > 3u || tot == 0u) {
            lo = 3u << 30;                   // OVF -> finish full-scans this row
        } else {
            uint32_t a0 = c0, a1 = c1, a2 = c2;
            if (cnt == 0u)      { a0 = p0; a1 = p1; a2 = p2; }
            else if (cnt == 1u) { a1 = p0; a2 = p1; }
            else if (cnt == 2u) { a2 = p0; }
            if (tot < 2u) a1 = 0u;
            if (tot < 3u) a2 = 0u;
            lo = ((tot - 1u) << 30) | (a0 & 1023u) | ((a1 & 1023u) << 10) | ((a2 & 1023u) << 20);
        }
        lockey[(size_t)(n0 + rowl) * 8 + cg] = lo;
    }
}

// ---------------------------------------------------------------------------
// finish kernel (R11): 1024 blocks x 256 thr, 32 rows/block.
// No prune: every cg's <=3 candidates are rechecked (union <= 24/row, so the
// winner — provably in its own cg's list or that cg OVFs — is always among
// them). Parallel: one exact_key per thread across 768 slots (3 predicated
// rounds); per-cg-OVF rows get a block-cooperative full 1024-code scan.
// exact_key_bn / norm64v / key+tie rule bit-identical to R5/R7 -> absmax 0.0.
// ---------------------------------------------------------------------------
__global__ __launch_bounds__(256)
void finish_kernel(const float* __restrict__ z_e, const float* __restrict__ emb,
                   const uint32_t* __restrict__ lockey,
                   const float* __restrict__ Bn_g,
                   uint32_t* __restrict__ counts, double* __restrict__ lp,
                   float* __restrict__ out) {
    __shared__ float zs[32 * 68];
    __shared__ float arow[32];                 // exact ||x||^2 per row
    __shared__ uint32_t scode[32];
    __shared__ uint8_t ncarr[32];              // 1=done, 2..24=pairs, 255=OVF
    __shared__ unsigned long long pkey[32][24];
    __shared__ uint32_t pairbuf[32 * 24];
    __shared__ uint32_t ovfbuf[32];
    __shared__ uint32_t novf;
    __shared__ unsigned long long rbuf[4];
    __shared__ double lred[4];
    const int t = threadIdx.x, lane = t & 63, wv = t >> 6;
    const int n0 = blockIdx.x * 32;                // rows n0..n0+31, same b
    const int b = n0 >> 10, hw0 = n0 & 1023;
    const int hwi = t & 31, dg = t >> 5;           // dg = 0..7
    const size_t base = (size_t)b * 65536 + (size_t)(dg * 8) * 1024 + hw0 + hwi;

    if (t == 0) novf = 0u;

    // load z (coalesced 128B per quarter-wave), keep in regs, stage to LDS
    float zreg[8];
#pragma unroll
    for (int k = 0; k < 8; ++k) zreg[k] = z_e[base + (size_t)k * 1024];
#pragma unroll
    for (int m = 0; m < 2; ++m)
        *(float4*)&zs[hwi * 68 + dg * 8 + 4 * m] =
            make_float4(zreg[4 * m], zreg[4 * m + 1], zreg[4 * m + 2], zreg[4 * m + 3]);
    __syncthreads();

    // ---- decode: gather all candidates from all 8 cgs ----
    if (t < 32) {
        const uint32_t* k8 = lockey + (size_t)(n0 + t) * 8;
        int nc = 0; bool ovf = false;
#pragma unroll
        for (int i = 0; i < 8; ++i) {
            uint32_t lo = k8[i];
            uint32_t cc = lo >> 30;
            if (cc == 3u) { ovf = true; }
            else {
#pragma unroll
                for (uint32_t q = 0; q < 3u; ++q)
                    if (q <= cc) { pairbuf[t * 24 + nc] = (lo >> (10u * q)) & 1023u; ++nc; }
            }
        }
        float A = norm64v((const float4*)&zs[t * 68]);
        arow[t] = A;
        if (ovf || nc == 0) {
            ncarr[t] = 255u;
            ovfbuf[atomicAdd(&novf, 1u)] = (uint32_t)t;
        } else if (nc == 1) {
            ncarr[t] = 1u;
            scode[t] = pairbuf[t * 24];        // provably the numpy argmin
        } else {
            ncarr[t] = (uint8_t)nc;            // 2..24
        }
    }
    __syncthreads();

    // ---- parallel exact rechecks: one (row,slot) per thread, predicated ----
#pragma unroll 1
    for (int p = t; p < 32 * 24; p += 256) {
        int row = p / 24, slot = p - row * 24;
        uint8_t nc = ncarr[row];
        if (nc >= 2u && nc != 255u && slot < (int)nc)
            pkey[row][slot] = exact_key_bn(arow[row], &zs[row * 68], emb, Bn_g, pairbuf[p]);
    }
    __syncthreads();

    // ---- OVF rows (rare): block-cooperative full 1024-code exact scan ----
    for (uint32_t o = 0; o < novf; ++o) {
        int row = (int)ovfbuf[o];
        const float* xr = &zs[row * 68];
        float A = arow[row];
        unsigned long long best = ~0ULL;
#pragma unroll 1
        for (int cq = 0; cq < 4; ++cq) {
            unsigned long long key = exact_key_bn(A, xr, emb, Bn_g, (uint32_t)(t + cq * 256));
            best = (key < best) ? key : best;
        }
#pragma unroll
        for (int m = 1; m < 64; m <<= 1) {
            unsigned long long ok = __shfl_xor(best, m, 64);
            best = (ok < best) ? ok : best;
        }
        if (lane == 0) rbuf[wv] = best;
        __syncthreads();
        if (t == 0) {
            unsigned long long bb = rbuf[0];
#pragma unroll
            for (int w = 1; w < 4; ++w) bb = (rbuf[w] < bb) ? rbuf[w] : bb;
            scode[row] = (uint32_t)bb;
        }
        __syncthreads();
    }

    // ---- resolve multi-candidate rows (ties -> lowest code, numpy) ----
    if (t < 32) {
        uint8_t nc = ncarr[t];
        if (nc >= 2u && nc != 255u) {
            unsigned long long bb = pkey[t][0];
#pragma unroll 1
            for (int q = 1; q < (int)nc; ++q)
                if (pkey[t][q] < bb) bb = pkey[t][q];
            scode[t] = (uint32_t)bb;
        }
    }
    __syncthreads();

    if (t < 32) {
        uint32_t code = scode[t];
        atomicAdd(&counts[code], 1u);
        out[(size_t)OUT_ENC + (size_t)(n0 + t) * 1024 + code] = 1.0f;
    }

    // z_st + loss from registers (exact per-element math unchanged)
    {
        const uint32_t code = scode[hwi];
        const float4* er4 = (const float4*)(emb + (size_t)code * 64) + dg * 2;
        double ls = 0.0;
#pragma unroll
        for (int k4 = 0; k4 < 2; ++k4) {
            float4 e4 = er4[k4];
            float f0 = e4.x, f1 = e4.y, f2 = e4.z, f3 = e4.w;
            size_t off = base + (size_t)(k4 * 4) * 1024;
            {
                float z = zreg[k4 * 4 + 0]; float tt = f0 - z;
                out[off] = z + tt;              ls += (double)tt * (double)tt;
            }
            {
                float z = zreg[k4 * 4 + 1]; float tt = f1 - z;
                out[off + 1024] = z + tt;       ls += (double)tt * (double)tt;
            }
            {
                float z = zreg[k4 * 4 + 2]; float tt = f2 - z;
                out[off + 2048] = z + tt;       ls += (double)tt * (double)tt;
            }
            {
                float z = zreg[k4 * 4 + 3]; float tt = f3 - z;
                out[off + 3072] = z + tt;       ls += (double)tt * (double)tt;
            }
        }
#pragma unroll
        for (int m = 32; m >= 1; m >>= 1) ls += __shfl_down(ls, m, 64);
        if ((t & 63) == 0) lred[t >> 6] = ls;
    }
    __syncthreads();
    if (t == 0) lp[blockIdx.x] = lred[0] + lred[1] + lred[2] + lred[3];
}

// ---------------------------------------------------------------------------
// scalar kernel: one block; sum 1024 fp64 loss partials + counts entropy.
// Stream ordering (kernel boundary) provides coherence — no fence needed.
// ---------------------------------------------------------------------------
__global__ void scalar_kernel(const uint32_t* __restrict__ counts,
                              const double* __restrict__ lp,
                              float* __restrict__ out) {
    __shared__ double redl[4], redh[4];
    const int t = threadIdx.x;   // 256
    double ls = 0.0;
    for (int i = t; i < 1024; i += 256) ls += lp[i];
    double h = 0.0;
    for (int i = t; i < Kk; i += 256) {
        double p = (double)counts[i] * (1.0 / 32768.0);
        h += p * log(p + 1e-10);
    }
#pragma unroll
    for (int m = 32; m >= 1; m >>= 1) { ls += __shfl_down(ls, m, 64); h += __shfl_down(h, m, 64); }
    if ((t & 63) == 0) { redl[t >> 6] = ls; redh[t >> 6] = h; }
    __syncthreads();
    if (t == 0) {
        double L = redl[0] + redl[1] + redl[2] + redl[3];
        double H = redh[0] + redh[1] + redh[2] + redh[3];
        out[OUT_PERP] = (float)exp(-H);
        float m32 = (float)(L * (1.0 / 2097152.0));
        out[OUT_LOSS] = m32 + 0.25f * m32;   // q + 0.25*e, q==e numerically
    }
}

extern "C" void kernel_launch(void* const* d_in, const int* in_sizes, int n_in,
                              void* d_out, int out_size, void* d_ws, size_t ws_size,
                              hipStream_t stream) {
    const float* z_e = (const float*)d_in[0];
    const float* emb = (const float*)d_in[1];
    float* out = (float*)d_out;
    char* ws = (char*)d_ws;

    uint32_t* counts = (uint32_t*)(ws + WS_CNT);
    double*   lp     = (double*)(ws + WS_LP);
    float*    Bn_g   = (float*)(ws + WS_BN);
    float*    mbn    = (float*)(ws + WS_MBN);
    uint32_t* lockey = (uint32_t*)(ws + WS_KEY);

    // no memsets: counts zeroed by norms block 0; Bn_g/maxbn/lockey/lp fully
    // written; enc zeros laid down by dist's interleaved fill (R10 A/B-proven
    // ~free vs a separate 20.5us fill dispatch).
    norms_kernel<<<4, 256, 0, stream>>>(emb, Bn_g, mbn, counts);
    dist_mfma<<<2048, 256, 0, stream>>>(z_e, emb, Bn_g, mbn, lockey, out);
    finish_kernel<<<1024, 256, 0, stream>>>(z_e, emb, lockey, Bn_g, counts, lp, out);
    scalar_kernel<<<1, 256, 0, stream>>>(counts, lp, out);
}

// Round 8
// 197.147 us; speedup vs baseline: 1.5779x; 1.5779x over previous
//
#include <hip/hip_runtime.h>
#include <stdint.h>
#include <math.h>

// Problem constants
constexpr int Kk  = 1024;

// d_out layout (floats)
constexpr int OUT0_N   = 32 * 64 * 1024;       // 2097152 (z_st, [B,D,H,W])
constexpr int OUT_LOSS = OUT0_N;               // 2097152
constexpr int OUT_PERP = OUT0_N + 1;           // 2097153
constexpr int OUT_ENC  = OUT0_N + 2;           // 2097154

// d_ws layout (bytes) — everything fully written each call (ws is poisoned):
//   [0      .. 4096)     counts u32[1024]     (zeroed by norms block 0)
//   [4096   .. 12288)    loss partials double[1024] (fully written by finish)
//   [12288  .. 16384)    Bn_g f32[1024]       exact code norms (norms_kernel)
//   [16384  .. 16416)    maxbn f32[8]         PER-CG max code norm
//   [16416  .. 2113568)  lockey u64[32768][8] per-(row,cg): {local-min f32 hi,
//                        cnt+3x10b candidate codes lo} — PLAIN stores.
// R12 = R11's dist/norms (x-from-global frags, precomputed Bn: dist ~45us)
//     + R9's finish (PRUNE + fast path: ~10us). R11 lesson: without the
//     local-min prune every row rechecks 8-24 candidates -> finish 140us.
constexpr size_t WS_CNT = 0;
constexpr size_t WS_LP  = 4096;
constexpr size_t WS_BN  = 12288;
constexpr size_t WS_MBN = 16384;
constexpr size_t WS_KEY = 16416;

typedef short bf16x8 __attribute__((ext_vector_type(8)));
typedef float f32x16 __attribute__((ext_vector_type(16)));

// ---------------------------------------------------------------------------
// numpy-bit-exact 64-elem squared-norm: tt[d]=fl(x*x), 8 stride-8 sequential
// accumulators, pairwise combine. Contraction OFF. p: 16B-aligned, contiguous.
// ---------------------------------------------------------------------------
__device__ __forceinline__ float norm64v(const float4* __restrict__ p) {
#pragma clang fp contract(off)
    float tt[64];
#pragma unroll
    for (int q = 0; q < 16; ++q) {
        float4 v = p[q];
        tt[4 * q + 0] = v.x * v.x;
        tt[4 * q + 1] = v.y * v.y;
        tt[4 * q + 2] = v.z * v.z;
        tt[4 * q + 3] = v.w * v.w;
    }
    float r[8];
#pragma unroll
    for (int j = 0; j < 8; ++j) r[j] = tt[j];
#pragma unroll
    for (int i = 8; i < 64; i += 8)
#pragma unroll
        for (int j = 0; j < 8; ++j) r[j] += tt[i + j];
    return ((r[0] + r[1]) + (r[2] + r[3])) + ((r[4] + r[5]) + (r[6] + r[7]));
}

__device__ __forceinline__ uint32_t fsort(float f) {
    uint32_t b = __float_as_uint(f);
    return (b & 0x80000000u) ? ~b : (b | 0x80000000u);
}

// RNE float->bf16 (finite inputs only; data is well inside normal range)
__device__ __forceinline__ unsigned short f2bf(float f) {
    uint32_t u = __float_as_uint(f);
    uint32_t r = (u + 0x7fffu + ((u >> 16) & 1u)) >> 16;
    return (unsigned short)r;
}

// exact distance key, bit-identical to the R5/R7 exact kernel; Bn_g holds the
// bit-exact norm64v value (computed once in norms_kernel from the same data).
__device__ __forceinline__ unsigned long long
exact_key_bn(float A, const float* __restrict__ xr, const float* __restrict__ emb,
             const float* __restrict__ Bn_g, uint32_t code) {
    const float* er = emb + (size_t)code * 64;
    float C = 0.f;
#pragma unroll
    for (int d = 0; d < 64; ++d) C = __builtin_fmaf(xr[d], er[d], C);
    float s = A + Bn_g[code];
    float dist = __builtin_fmaf(-2.f, C, s);
    return ((unsigned long long)fsort(dist) << 32) | code;
}

// ---------------------------------------------------------------------------
// norms_kernel: 4 blocks x 256 thr — exact code norms ONCE, PER-CG max norms
// (block i covers cgs 2i,2i+1: waves 0-1 / 2-3), counts zero.
// ---------------------------------------------------------------------------
__global__ __launch_bounds__(256)
void norms_kernel(const float* __restrict__ emb, float* __restrict__ Bn_g,
                  float* __restrict__ maxbn, uint32_t* __restrict__ counts) {
    __shared__ float wred[4];
    const int t = threadIdx.x, lane = t & 63, wv = t >> 6;
    const int code = blockIdx.x * 256 + t;
    float nn = norm64v((const float4*)(emb + (size_t)code * 64));
    Bn_g[code] = nn;
    if (blockIdx.x == 0) ((uint4*)counts)[t] = make_uint4(0u, 0u, 0u, 0u);
    float mx = nn;
#pragma unroll
    for (int m = 1; m < 64; m <<= 1) mx = fmaxf(mx, __shfl_xor(mx, m, 64));
    if (lane == 0) wred[wv] = mx;
    __syncthreads();
    if (t == 0)   maxbn[blockIdx.x * 2 + 0] = fmaxf(wred[0], wred[1]);
    if (t == 128) maxbn[blockIdx.x * 2 + 1] = fmaxf(wred[2], wred[3]);
}

// ---------------------------------------------------------------------------
// dist_mfma (R12 = R11 structure + u64 {lmin,cands} key): 2048 blocks =
// 256 rowgroups x 8 codegroups, 256 thr, ~17 KB LDS, 4 blk/CU.
// Screen: s_hat = Bn_exact - 2*(x.e)_bf16 via mfma_32x32x16_bf16; margin
// 0.017*sqrt(xsq*maxBn_cg)+1e-4 (validated R6/R8/R9, absmax 0.0 each time).
// x B-fragments straight from global (same (s,g,e)->d map as validated);
// Bn_s from precomputed Bn_g (bit-identical). Enc zero-fill interleave kept
// (R10 A/B: ~free here vs +20.5us as a separate fill dispatch).
// ---------------------------------------------------------------------------
__global__ __launch_bounds__(256, 4)
void dist_mfma(const float* __restrict__ z_e, const float* __restrict__ emb,
               const float* __restrict__ Bn_g, const float* __restrict__ maxbn,
               unsigned long long* __restrict__ lockey, float* __restrict__ out) {
    __shared__ unsigned short ebf[128 * 64];   // 16 KB bf16 codes, swizzled
    __shared__ float Bn_s[128];
    const int t = threadIdx.x, lane = t & 63, wv = t >> 6, g = lane >> 5;
    const int rg = blockIdx.x >> 3, cg = blockIdx.x & 7;
    const int n0 = rg * 128, b = n0 >> 10, hw0 = n0 & 1023;
    const float* zb = z_e + (size_t)b * 65536 + hw0;

    // ---- e-tile: contiguous 32 KB fp32 -> bf16 LDS (swizzled) ----
    {
        const float4* ep = (const float4*)(emb + (size_t)cg * 8192);
#pragma unroll
        for (int it = 0; it < 8; ++it) {
            int j = t + it * 256;            // 0..2047
            float4 v = ep[j];
            int code = j >> 4, q = j & 15;
            ushort4 bv;
            bv.x = f2bf(v.x); bv.y = f2bf(v.y); bv.z = f2bf(v.z); bv.w = f2bf(v.w);
            *(ushort4*)((char*)ebf + code * 128 + ((q * 8) ^ ((code & 7) << 4))) = bv;
        }
    }
    if (t < 128) Bn_s[t] = Bn_g[cg * 128 + t];    // bit-exact precomputed norms

    // ---- x B-fragments: straight from global to registers (no LDS) ----
    const int rowl = wv * 32 + (lane & 31);
    float xsq = 0.f;
    bf16x8 bfr[4];
#pragma unroll
    for (int s = 0; s < 4; ++s) {
        bf16x8 f;
#pragma unroll
        for (int e = 0; e < 8; ++e) {
            int d = s * 16 + g * 8 + e;
            float x = zb[(size_t)d * 1024 + rowl];
            xsq = __builtin_fmaf(x, x, xsq);
            f[e] = (short)f2bf(x);
        }
        bfr[s] = f;
    }
    xsq += __shfl_xor(xsq, 32, 64);          // partner half holds other 32 d's
    const float margin = 0.017f * sqrtf(xsq * maxbn[cg]) + 1.0e-4f;
    __syncthreads();

    const int swz = (lane & 7) << 4;
    const char* ebase = (const char*)ebf + (lane & 31) * 128;

    float4* encz = (float4*)(out + OUT_ENC) + (size_t)blockIdx.x * 4096;
    const float4 zero4 = make_float4(0.f, 0.f, 0.f, 0.f);

    // ---- pass 1: row min of s_hat (enc-fill stores ride along) ----
    float runmin = 3.4e38f;
#pragma unroll 1
    for (int tm = 0; tm < 4; ++tm) {
        encz[(size_t)(tm * 2 + 0) * 256 + t] = zero4;
        encz[(size_t)(tm * 2 + 1) * 256 + t] = zero4;
        const char* p = ebase + tm * 4096;
        f32x16 acc = {};
#pragma unroll
        for (int s = 0; s < 4; ++s)
            acc = __builtin_amdgcn_mfma_f32_32x32x16_bf16(
                *(const bf16x8*)(p + ((s * 32 + g * 16) ^ swz)), bfr[s], acc, 0, 0, 0);
#pragma unroll
        for (int r = 0; r < 16; ++r) {
            int cl = tm * 32 + (r & 3) + 8 * (r >> 2) + 4 * g;
            runmin = fminf(runmin, __builtin_fmaf(-2.f, acc[r], Bn_s[cl]));
        }
    }
    runmin = fminf(runmin, __shfl_xor(runmin, 32, 64));   // lane pair = same row
    const float thr = runmin + margin;

    // ---- pass 2: collect candidates (<=3/lane; MFMA recompute, cheap) ----
    uint32_t cnt = 0, c0 = 0, c1 = 0, c2 = 0;
#pragma unroll 1
    for (int tm = 0; tm < 4; ++tm) {
        encz[(size_t)(8 + tm * 2 + 0) * 256 + t] = zero4;
        encz[(size_t)(8 + tm * 2 + 1) * 256 + t] = zero4;
        const char* p = ebase + tm * 4096;
        f32x16 acc = {};
#pragma unroll
        for (int s = 0; s < 4; ++s)
            acc = __builtin_amdgcn_mfma_f32_32x32x16_bf16(
                *(const bf16x8*)(p + ((s * 32 + g * 16) ^ swz)), bfr[s], acc, 0, 0, 0);
#pragma unroll
        for (int r = 0; r < 16; ++r) {
            int cl = tm * 32 + (r & 3) + 8 * (r >> 2) + 4 * g;
            float sv = __builtin_fmaf(-2.f, acc[r], Bn_s[cl]);
            if (sv <= thr) {
                uint32_t gc = (uint32_t)(cg * 128 + cl);
                if (cnt == 0u) c0 = gc; else if (cnt == 1u) c1 = gc; else if (cnt == 2u) c2 = gc;
                ++cnt;
            }
        }
    }
    // merge with partner lane (lane^32: other code-subset of the same row)
    uint32_t pc = __shfl_xor(cnt, 32, 64);
    uint32_t p0 = __shfl_xor(c0, 32, 64);
    uint32_t p1 = __shfl_xor(c1, 32, 64);
    uint32_t p2 = __shfl_xor(c2, 32, 64);
    if (lane < 32) {
        uint32_t tot = cnt + pc;
        uint32_t lo;
        if (tot > 3u || tot == 0u) {
            lo = 3u << 30;                   // OVF marker for this cg
        } else {
            uint32_t a0 = c0, a1 = c1, a2 = c2;
            if (cnt == 0u)      { a0 = p0; a1 = p1; a2 = p2; }
            else if (cnt == 1u) { a1 = p0; a2 = p1; }
            else if (cnt == 2u) { a2 = p0; }
            if (tot < 2u) a1 = 0u;
            if (tot < 3u) a2 = 0u;
            lo = ((tot - 1u) << 30) | (a0 & 1023u) | ((a1 & 1023u) << 10) | ((a2 & 1023u) << 20);
        }
        unsigned long long key = ((unsigned long long)__float_as_uint(runmin) << 32) | lo;
        lockey[(size_t)(n0 + rowl) * 8 + cg] = key;
    }
}

// ---------------------------------------------------------------------------
// finish kernel (R9 structure restored — measured <=10us there): 1024 blocks
// x 256 thr, 32 rows/block. PRUNE cgs by local_min > gmin + margin_global
// (winner's cg provably survives); 1-candidate fast path (the common case);
// parallel exact rechecks (one exact_key per thread); block-cooperative OVF
// scans. exact_key_bn / norm64v / key+tie rule bit-identical -> absmax 0.0.
// ---------------------------------------------------------------------------
__global__ __launch_bounds__(256)
void finish_kernel(const float* __restrict__ z_e, const float* __restrict__ emb,
                   const unsigned long long* __restrict__ lockey,
                   const float* __restrict__ Bn_g,
                   const float* __restrict__ maxbn,
                   uint32_t* __restrict__ counts, double* __restrict__ lp,
                   float* __restrict__ out) {
    __shared__ float zs[32 * 68];
    __shared__ float arow[32];                 // exact ||x||^2 per row
    __shared__ uint32_t scode[32];
    __shared__ uint8_t ncarr[32];              // 1=done, 2..6=pairs, 255=OVF
    __shared__ unsigned long long pkey[32][6];
    __shared__ uint32_t pairbuf[192];
    __shared__ uint32_t ovfbuf[32];
    __shared__ uint32_t npairs, novf;
    __shared__ float mbg_s;
    __shared__ unsigned long long rbuf[4];
    __shared__ double lred[4];
    const int t = threadIdx.x, lane = t & 63, wv = t >> 6;
    const int n0 = blockIdx.x * 32;                // rows n0..n0+31, same b
    const int b = n0 >> 10, hw0 = n0 & 1023;
    const int hwi = t & 31, dg = t >> 5;           // dg = 0..7
    const size_t base = (size_t)b * 65536 + (size_t)(dg * 8) * 1024 + hw0 + hwi;

    if (t == 0) {
        npairs = 0u; novf = 0u;
        float mb = maxbn[0];
#pragma unroll
        for (int i = 1; i < 8; ++i) mb = fmaxf(mb, maxbn[i]);
        mbg_s = mb;
    }

    // load z (coalesced 128B per quarter-wave), keep in regs, stage to LDS
    float zreg[8];
#pragma unroll
    for (int k = 0; k < 8; ++k) zreg[k] = z_e[base + (size_t)k * 1024];
#pragma unroll
    for (int m = 0; m < 2; ++m)
        *(float4*)&zs[hwi * 68 + dg * 8 + 4 * m] =
            make_float4(zreg[4 * m], zreg[4 * m + 1], zreg[4 * m + 2], zreg[4 * m + 3]);
    __syncthreads();

    // ---- decode: prune cgs, classify each row ----
    if (t < 32) {
        const unsigned long long* k8 = lockey + (size_t)(n0 + t) * 8;
        unsigned long long kws[8];
#pragma unroll
        for (int i = 0; i < 8; ++i) kws[i] = k8[i];
        float gmin = 3.4e38f;
#pragma unroll
        for (int i = 0; i < 8; ++i)
            gmin = fminf(gmin, __uint_as_float((uint32_t)(kws[i] >> 32)));
        float A = norm64v((const float4*)&zs[t * 68]);
        arow[t] = A;
        const float thr = gmin + 0.017f * sqrtf(A * mbg_s) + 1.0e-4f;

        int nc = 0; uint32_t cand[6]; bool ovf = false;
#pragma unroll
        for (int i = 0; i < 8; ++i) {
            float f = __uint_as_float((uint32_t)(kws[i] >> 32));
            if (f > thr) continue;              // prune: cg can't hold winner
            uint32_t lo = (uint32_t)kws[i], cc = lo >> 30;
            if (cc == 3u) { ovf = true; }
            else {
#pragma unroll
                for (uint32_t q = 0; q < 3u; ++q)
                    if (q <= cc) {
                        if (nc < 6) cand[nc] = (lo >> (10u * q)) & 1023u;
                        ++nc;
                    }
            }
        }
        if (ovf || nc > 6 || nc == 0) {
            ncarr[t] = 255u;
            ovfbuf[atomicAdd(&novf, 1u)] = (uint32_t)t;
        } else if (nc == 1) {
            ncarr[t] = 1u;
            scode[t] = cand[0];                // provably the numpy argmin
        } else {
            ncarr[t] = (uint8_t)nc;
            uint32_t bs = atomicAdd(&npairs, (uint32_t)nc);
#pragma unroll
            for (int q = 0; q < 6; ++q)
                if (q < nc)
                    pairbuf[bs + q] = ((uint32_t)t << 13) | ((uint32_t)q << 10) | cand[q];
        }
    }
    __syncthreads();

    // ---- parallel exact rechecks: one (row,code) per thread ----
    for (uint32_t p = t; p < npairs; p += 256u) {
        uint32_t pk = pairbuf[p];
        int row = (int)(pk >> 13), slot = (int)((pk >> 10) & 7u);
        pkey[row][slot] = exact_key_bn(arow[row], &zs[row * 68], emb, Bn_g, pk & 1023u);
    }
    __syncthreads();

    // ---- OVF rows (rare): block-cooperative full 1024-code exact scan ----
    for (uint32_t o = 0; o < novf; ++o) {
        int row = (int)ovfbuf[o];
        const float* xr = &zs[row * 68];
        float A = arow[row];
        unsigned long long best = ~0ULL;
#pragma unroll 1
        for (int cq = 0; cq < 4; ++cq) {
            unsigned long long key = exact_key_bn(A, xr, emb, Bn_g, (uint32_t)(t + cq * 256));
            best = (key < best) ? key : best;
        }
#pragma unroll
        for (int m = 1; m < 64; m <<= 1) {
            unsigned long long ok = __shfl_xor(best, m, 64);
            best = (ok < best) ? ok : best;
        }
        if (lane == 0) rbuf[wv] = best;
        __syncthreads();
        if (t == 0) {
            unsigned long long bb = rbuf[0];
#pragma unroll
            for (int w = 1; w < 4; ++w) bb = (rbuf[w] < bb) ? rbuf[w] : bb;
            scode[row] = (uint32_t)bb;
        }
        __syncthreads();
    }

    // ---- resolve multi-candidate rows (ties -> lowest code, numpy) ----
    if (t < 32) {
        uint8_t nc = ncarr[t];
        if (nc >= 2u && nc != 255u) {
            unsigned long long bb = pkey[t][0];
#pragma unroll
            for (int q = 1; q < 6; ++q)
                if (q < (int)nc && pkey[t][q] < bb) bb = pkey[t][q];
            scode[t] = (uint32_t)bb;
        }
    }
    __syncthreads();

    if (t < 32) {
        uint32_t code = scode[t];
        atomicAdd(&counts[code], 1u);
        out[(size_t)OUT_ENC + (size_t)(n0 + t) * 1024 + code] = 1.0f;
    }

    // z_st + loss from registers (exact per-element math unchanged)
    {
        const uint32_t code = scode[hwi];
        const float4* er4 = (const float4*)(emb + (size_t)code * 64) + dg * 2;
        double ls = 0.0;
#pragma unroll
        for (int k4 = 0; k4 < 2; ++k4) {
            float4 e4 = er4[k4];
            float f0 = e4.x, f1 = e4.y, f2 = e4.z, f3 = e4.w;
            size_t off = base + (size_t)(k4 * 4) * 1024;
            {
                float z = zreg[k4 * 4 + 0]; float tt = f0 - z;
                out[off] = z + tt;              ls += (double)tt * (double)tt;
            }
            {
                float z = zreg[k4 * 4 + 1]; float tt = f1 - z;
                out[off + 1024] = z + tt;       ls += (double)tt * (double)tt;
            }
            {
                float z = zreg[k4 * 4 + 2]; float tt = f2 - z;
                out[off + 2048] = z + tt;       ls += (double)tt * (double)tt;
            }
            {
                float z = zreg[k4 * 4 + 3]; float tt = f3 - z;
                out[off + 3072] = z + tt;       ls += (double)tt * (double)tt;
            }
        }
#pragma unroll
        for (int m = 32; m >= 1; m >>= 1) ls += __shfl_down(ls, m, 64);
        if ((t & 63) == 0) lred[t >> 6] = ls;
    }
    __syncthreads();
    if (t == 0) lp[blockIdx.x] = lred[0] + lred[1] + lred[2] + lred[3];
}

// ---------------------------------------------------------------------------
// scalar kernel: one block; sum 1024 fp64 loss partials + counts entropy.
// Stream ordering (kernel boundary) provides coherence — no fence needed.
// ---------------------------------------------------------------------------
__global__ void scalar_kernel(const uint32_t* __restrict__ counts,
                              const double* __restrict__ lp,
                              float* __restrict__ out) {
    __shared__ double redl[4], redh[4];
    const int t = threadIdx.x;   // 256
    double ls = 0.0;
    for (int i = t; i < 1024; i += 256) ls += lp[i];
    double h = 0.0;
    for (int i = t; i < Kk; i += 256) {
        double p = (double)counts[i] * (1.0 / 32768.0);
        h += p * log(p + 1e-10);
    }
#pragma unroll
    for (int m = 32; m >= 1; m >>= 1) { ls += __shfl_down(ls, m, 64); h += __shfl_down(h, m, 64); }
    if ((t & 63) == 0) { redl[t >> 6] = ls; redh[t >> 6] = h; }
    __syncthreads();
    if (t == 0) {
        double L = redl[0] + redl[1] + redl[2] + redl[3];
        double H = redh[0] + redh[1] + redh[2] + redh[3];
        out[OUT_PERP] = (float)exp(-H);
        float m32 = (float)(L * (1.0 / 2097152.0));
        out[OUT_LOSS] = m32 + 0.25f * m32;   // q + 0.25*e, q==e numerically
    }
}

extern "C" void kernel_launch(void* const* d_in, const int* in_sizes, int n_in,
                              void* d_out, int out_size, void* d_ws, size_t ws_size,
                              hipStream_t stream) {
    const float* z_e = (const float*)d_in[0];
    const float* emb = (const float*)d_in[1];
    float* out = (float*)d_out;
    char* ws = (char*)d_ws;

    uint32_t* counts = (uint32_t*)(ws + WS_CNT);
    double*   lp     = (double*)(ws + WS_LP);
    float*    Bn_g   = (float*)(ws + WS_BN);
    float*    mbn    = (float*)(ws + WS_MBN);
    unsigned long long* lockey = (unsigned long long*)(ws + WS_KEY);

    // no memsets: counts zeroed by norms block 0; Bn_g/maxbn/lockey/lp fully
    // written; enc zeros laid down by dist's interleaved fill.
    norms_kernel<<<4, 256, 0, stream>>>(emb, Bn_g, mbn, counts);
    dist_mfma<<<2048, 256, 0, stream>>>(z_e, emb, Bn_g, mbn, lockey, out);
    finish_kernel<<<1024, 256, 0, stream>>>(z_e, emb, lockey, Bn_g, mbn, counts, lp, out);
    scalar_kernel<<<1, 256, 0, stream>>>(counts, lp, out);
}